// Round 6
// baseline (218.740 us; speedup 1.0000x reference)
//
#include <hip/hip_runtime.h>
#include <hip/hip_bf16.h>

// Problem constants (from reference)
#define BATCH_N   16384
#define FEAT      128      // MOVIE_FEAT == USER_FEAT
#define NNBR      50
#define NUM_MOVIES_N 100000

typedef short  short8  __attribute__((ext_vector_type(8)));
typedef float  floatx4 __attribute__((ext_vector_type(4)));
typedef unsigned int u32;

__device__ __forceinline__ __hip_bfloat16 f2bf(float x) { return __float2bfloat16(x); }
__device__ __forceinline__ float bfb2f(short s) {
  union { u32 u; float f; } c; c.u = ((u32)(unsigned short)s) << 16; return c.f;
}

// async global->LDS 16B DMA. HW writes wave-uniform base + lane*16 (m104);
// the per-lane pointer we pass must equal that form.
__device__ __forceinline__ void gld16(const __hip_bfloat16* g, __hip_bfloat16* l) {
  __builtin_amdgcn_global_load_lds(
      (const __attribute__((address_space(1))) u32*)g,
      (__attribute__((address_space(3))) u32*)l, 16, 0, 0);
}

__device__ __forceinline__ floatx4 mfma16(short8 a, short8 b, floatx4 c) {
  return __builtin_amdgcn_mfma_f32_16x16x32_bf16(a, b, c, 0, 0, 0);
}

#define WAITVM2 asm volatile("s_waitcnt vmcnt(2)" ::: "memory")
#define WAITVM0 asm volatile("s_waitcnt vmcnt(0)" ::: "memory")

// ---------------------------------------------------------------------------
// prep_all: fused (a) fp32 movie_table -> bf16 copy and (b) bf16 transposed
// weights Wt[n][k] + fused bias bu+bm. One launch instead of two.
// blocks [0,6250): conv;  [6250,6506): weight prep.
// ---------------------------------------------------------------------------
#define CONV_BLOCKS (NUM_MOVIES_N * FEAT / (256 * 8))   // 6250
__global__ __launch_bounds__(256) void prep_all(
    const float* __restrict__ t, __hip_bfloat16* __restrict__ tb,
    const float* __restrict__ Wu, const float* __restrict__ Wm,
    const float* __restrict__ W1, const float* __restrict__ W2,
    const float* __restrict__ bu, const float* __restrict__ bm,
    __hip_bfloat16* __restrict__ WcatT, __hip_bfloat16* __restrict__ WmT,
    __hip_bfloat16* __restrict__ W1T,  __hip_bfloat16* __restrict__ W2T,
    float* __restrict__ bc) {
  int bid = blockIdx.x;
  if (bid < CONV_BLOCKS) {
    size_t i = ((size_t)bid * 256 + threadIdx.x) * 8;
    float4 v0 = *(const float4*)(t + i);
    float4 v1 = *(const float4*)(t + i + 4);
    __hip_bfloat16 o[8];
    o[0] = f2bf(v0.x); o[1] = f2bf(v0.y); o[2] = f2bf(v0.z); o[3] = f2bf(v0.w);
    o[4] = f2bf(v1.x); o[5] = f2bf(v1.y); o[6] = f2bf(v1.z); o[7] = f2bf(v1.w);
    *(short8*)(tb + i) = *(short8*)o;
  } else {
    int idx = (bid - CONV_BLOCKS) * 256 + threadIdx.x;   // 0..65535
    int n = idx & 255, k = idx >> 8;
    float v = (k < 128) ? Wu[k * 256 + n] : Wm[(k - 128) * 256 + n];
    WcatT[n * 256 + k] = f2bf(v);
    W1T[n * 256 + k]   = f2bf(W1[k * 256 + n]);
    if (k < 128) WmT[n * 128 + k] = f2bf(Wm[k * 256 + n]);
    if (idx < 32768) {
      int k2 = idx >> 7, n2 = idx & 127;
      W2T[n2 * 256 + k2] = f2bf(W2[k2 * 128 + n2]);
    }
    if (idx < 256) bc[idx] = bu[idx] + bm[idx];
  }
}

// ---------------------------------------------------------------------------
// layer: one GEMM layer on an MROWS-row LDS tile with B persistent in VGPRs.
//   Ain (LDS): MROWS rows x K0, XOR-swizzled (16B slot s holds chunk s^(r&7)).
//   Wt: global [NCOL][K0] bf16 (L2-hot; ~16 KB/wave loaded ONCE per layer).
// 8 waves split N: wave w owns JN*16 cols (JN = NCOL/128).
// MROWS/16 iters x 16 rows: KK ds_read_b128 + 2*KK*JN MFMA; epilogue -> LDS
// (swizzled, 256-col) or global fp32 (128-col).
// ---------------------------------------------------------------------------
template <int MROWS, int K0, int NCOL, bool RELU, bool TOGLB>
__device__ __forceinline__ void layer(
    const __hip_bfloat16* Ain,
    const __hip_bfloat16* __restrict__ Wt, const float* __restrict__ bias,
    __hip_bfloat16* Olds, float* __restrict__ Oglb,
    int wid, int quad, int lrow) {
  constexpr int KK = K0 / 32;
  constexpr int JN = NCOL / 128;
  const int c0 = wid * JN * 16;

  short8 bfr[JN][KK];
  float  bv[JN];
  #pragma unroll
  for (int j = 0; j < JN; ++j) {
    #pragma unroll
    for (int kc = 0; kc < KK; ++kc)
      bfr[j][kc] = *(const short8*)(Wt + (size_t)(c0 + j * 16 + lrow) * K0 +
                                    kc * 32 + quad * 8);
    bv[j] = bias[c0 + j * 16 + lrow];
  }

  #pragma unroll
  for (int it = 0; it < MROWS / 16; ++it) {
    int r = it * 16 + lrow;
    short8 af[KK];
    #pragma unroll
    for (int kc = 0; kc < KK; ++kc)
      af[kc] = *(const short8*)&Ain[r * K0 + (((kc * 4 + quad) ^ (r & 7)) << 3)];
    floatx4 pa[JN], pb[JN];
    #pragma unroll
    for (int j = 0; j < JN; ++j) { pa[j] = {}; pb[j] = {}; }
    #pragma unroll
    for (int kc = 0; kc < KK; kc += 2)
      #pragma unroll
      for (int j = 0; j < JN; ++j) {
        pa[j] = mfma16(af[kc],     bfr[j][kc],     pa[j]);
        pb[j] = mfma16(af[kc + 1], bfr[j][kc + 1], pb[j]);
      }
    #pragma unroll
    for (int j = 0; j < JN; ++j) {
      floatx4 a = pa[j] + pb[j];
      int col = c0 + j * 16 + lrow;
      #pragma unroll
      for (int rr = 0; rr < 4; ++rr) {
        int row = it * 16 + quad * 4 + rr;
        float v = a[rr] + bv[j];
        if (RELU) v = fmaxf(v, 0.f);
        if (TOGLB) {
          Oglb[(size_t)row * NCOL + col] = v;
        } else {
          int ch = col >> 3;
          Olds[row * 256 + (((ch ^ (row & 7)) << 3) | (col & 7))] = f2bf(v);
        }
      }
    }
  }
}

// ---------------------------------------------------------------------------
// fused_mlp: all 3 layers per block; B per layer in VGPRs, A/E/H in LDS.
//
// Pin history (do not change without re-reading):
//   R10: launch_bounds(512,2) alone -> 88 VGPR, B-loads sunk. R12: (4,4) ->
//   64-VGPR bucket, persistent-B spilled (WRITE 24.6->129.6 MB). (2,2) is
//   the only verified-good codegen.
//
// R16 (this round): R14 (~16 KB/wave in flight) == R15 (~2-4 KB/wave) at
// 68 us -> per-wave MLP is NOT the binding constraint; the per-CU request
// machinery saturates at ~8 gather-waves/CU, and only half the CUs held s0
// blocks. Fix: DOUBLE gather CU-participation. s0 tiles shrink to 32 rows
// -> 512 s0 blocks, interleaved even/odd with the 512 s1/s2 blocks so at
// t=0 each CU holds ~1 gather block + 1 MFMA block. Per-wave pipeline
// (2 KB chunks, vmcnt(2) dbuf, 4 rows x 7 chunks = 28 steps) unchanged.
// LDS (s0): A 16 KB [0,16K) | E 16 KB [32K,48K) | staging 32 KB [32K,64K)
// during gather only (E written post-barrier). s1/s2: A/H [0,32K), E [32K,64K).
// Accumulation order per lane identical to R15 -> bit-identical numerics.
// ---------------------------------------------------------------------------
__global__ __launch_bounds__(512)
__attribute__((amdgpu_waves_per_eu(2, 2)))
void fused_mlp(
    const float* __restrict__ users,
    const __hip_bfloat16* __restrict__ tb,
    const int* __restrict__ pos_ids, const int* __restrict__ neg_ids,
    const int* __restrict__ nbr_ids,
    const __hip_bfloat16* __restrict__ WcatT,
    const __hip_bfloat16* __restrict__ WmT,
    const __hip_bfloat16* __restrict__ W1T,
    const __hip_bfloat16* __restrict__ W2T,
    const float* __restrict__ bc, const float* __restrict__ bmv,
    const float* __restrict__ b1, const float* __restrict__ b2,
    float* __restrict__ out) {
  __shared__ char raw[65536];
  __hip_bfloat16* A_lds = (__hip_bfloat16*)raw;            // A, then H
  __hip_bfloat16* E_lds = (__hip_bfloat16*)(raw + 32768);  // staging / E

  const int t    = threadIdx.x;
  const int lane = t & 63, wid = t >> 6;       // wid 0..7
  const int quad = lane >> 4, lrow = lane & 15;

  // interleaved mapping: even blocks -> s0 (32-row tiles, 512 of them);
  // odd blocks -> s1/s2 (64-row tiles, 256 each).
  const int b = blockIdx.x;
  int s; long m0;
  if ((b & 1) == 0) { s = 0; m0 = (long)(b >> 1) * 32; }
  else { int k = b >> 1; s = 1 + (k & 1); m0 = (long)(k >> 1) * 64; }

  // ---- stage A tile ----
  if (s == 0) {
    const int rbase = wid << 2;                      // wave owns rows rbase..+3
    const int* nbw = nbr_ids + (size_t)(m0 + rbase) * NNBR;   // 200 ids
    // bulk id load: 4 coalesced loads, lane l holds flat ids l, l+64, ...
    int idreg[4];
    #pragma unroll
    for (int w = 0; w < 4; ++w) {
      int fl = w * 64 + lane;
      idreg[w] = nbw[fl < 4 * NNBR ? fl : 4 * NNBR - 1];
    }
    // user rows (4 loads; retire under the pipeline, used at row ends)
    float2 uvr[4];
    #pragma unroll
    for (int r = 0; r < 4; ++r)
      uvr[r] = ((const float2*)(users + (size_t)(m0 + rbase + r) * FEAT))[lane];

    __hip_bfloat16* stg = E_lds + (wid << 11);       // 4 KB slice (2 x 2 KB)

    // id for 4 consecutive flat slots [fb, fb+3], lane picks fb+quad.
    auto getid = [&](int fb) -> int {
      int idx = fb + quad;
      int v = __shfl(idreg[fb >> 6], idx & 63, 64);
      if ((fb >> 6) != ((fb + 3) >> 6)) {
        int v2 = __shfl(idreg[(fb + 3) >> 6], idx & 63, 64);
        v = ((idx >> 6) == (fb >> 6)) ? v : v2;
      }
      return v;
    };
    // chunk k: rows j = c*8 + i*4 + quad (i=0,1), slice lrow; 2 x 1 KB DMA.
    auto issue = [&](int k) {
      int row = k / 7, c = k % 7;
      int id0 = getid(row * NNBR + c * 8);
      int id1 = getid(row * NNBR + c * 8 + 4);
      __hip_bfloat16* dst = stg + ((k & 1) << 10);   // buf k&1 (2 KB)
      gld16(tb + (size_t)id0 * FEAT + (lrow << 3), dst + (lane << 3));
      gld16(tb + (size_t)id1 * FEAT + (lrow << 3), dst + 512 + (lane << 3));
    };

    issue(0); issue(1);                              // fill pipeline (4 DMA)
    float acc[8] = {0.f, 0.f, 0.f, 0.f, 0.f, 0.f, 0.f, 0.f};
    #pragma unroll
    for (int k = 0; k < 28; ++k) {                   // row = k/7, c = k%7
      if (k < 27) { WAITVM2; } else { WAITVM0; }     // chunk k retired
      const __hip_bfloat16* bb = stg + ((k & 1) << 10);
      int c = k % 7;
      short8 x0 = *(const short8*)(bb + (lane << 3));          // j = c*8+quad
      if (c < 6) {
        short8 x1 = *(const short8*)(bb + 512 + (lane << 3));  // j = c*8+4+quad
        #pragma unroll
        for (int e = 0; e < 8; ++e) { acc[e] += bfb2f(x0[e]); acc[e] += bfb2f(x1[e]); }
      } else if (quad < 2) {                         // j = 48+quad only
        #pragma unroll
        for (int e = 0; e < 8; ++e) acc[e] += bfb2f(x0[e]);
      }
      if (c == 6) {                                  // row complete
        int row = k / 7, r = rbase + row;
        __hip_bfloat16 o[8];
        #pragma unroll
        for (int e = 0; e < 8; ++e) {
          float v = acc[e];
          v += __shfl_xor(v, 16, 64);
          v += __shfl_xor(v, 32, 64);
          o[e] = f2bf(v * (1.f / NNBR));
          acc[e] = 0.f;
        }
        if (quad == 0) {
          int ch = 16 + lrow;                        // cols [128,256)
          *(short8*)(A_lds + r * 256 + ((ch ^ (r & 7)) << 3)) = *(short8*)o;
        }
        float2 uv = uvr[row];                        // cols [0,128)
        __hip_bfloat162 t0; t0.x = f2bf(uv.x); t0.y = f2bf(uv.y);
        int col = lane << 1, ch2 = col >> 3;
        *(__hip_bfloat162*)(A_lds + r * 256 + ((ch2 ^ (r & 7)) << 3) + (col & 7)) = t0;
      }
      __builtin_amdgcn_sched_barrier(0);             // ds_reads done before WAR reuse
      if (k + 2 < 28) issue(k + 2);
    }
  } else {
    const int* ids = (s == 1) ? pos_ids : neg_ids;
    #pragma unroll
    for (int i = 0; i < 2; ++i) {
      int c = t + i * 512;                     // 1024 slots: r=c>>4, sl=c&15
      int r = c >> 4, sl = c & 15;
      int id = ids[m0 + r];
      gld16(tb + ((size_t)id << 7) + ((sl ^ (r & 7)) << 3),
            A_lds + (c << 3));
    }
  }
  __syncthreads();                             // A staged (vmcnt(0) drain / LDS writes)

  if (s == 0) {
    // ---- 32-row tile; E uses first 16 KB of the staging region (now free)
    layer<32, 256, 256, false, false>(A_lds, WcatT, bc, E_lds, nullptr,
                                      wid, quad, lrow);
    __syncthreads();
    layer<32, 256, 256, true, false>(E_lds, W1T, b1, A_lds, nullptr,
                                     wid, quad, lrow);
    __syncthreads();
    layer<32, 256, 128, true, true>(A_lds, W2T, b2, nullptr,
                                    out + (size_t)m0 * 128,
                                    wid, quad, lrow);
  } else {
    layer<64, 128, 256, false, false>(A_lds, WmT, bmv, E_lds, nullptr,
                                      wid, quad, lrow);
    __syncthreads();
    layer<64, 256, 256, true, false>(E_lds, W1T, b1, A_lds, nullptr,
                                     wid, quad, lrow);
    __syncthreads();
    layer<64, 256, 128, true, true>(A_lds, W2T, b2, nullptr,
                                    out + ((size_t)s * BATCH_N + m0) * 128,
                                    wid, quad, lrow);
  }
}

// ---------------------------------------------------------------------------
extern "C" void kernel_launch(void* const* d_in, const int* in_sizes, int n_in,
                              void* d_out, int out_size, void* d_ws, size_t ws_size,
                              hipStream_t stream) {
  const float* users   = (const float*)d_in[0];
  // d_in[1] pos_movies, d_in[2] neg_movies, d_in[3] user_ids: unused by ref
  const int*   pos_ids = (const int*)d_in[4];
  const int*   neg_ids = (const int*)d_in[5];
  const int*   nbr_ids = (const int*)d_in[6];
  const float* table   = (const float*)d_in[7];
  const float* Wu = (const float*)d_in[8];
  const float* bu = (const float*)d_in[9];
  const float* Wm = (const float*)d_in[10];
  const float* bm = (const float*)d_in[11];
  const float* W1 = (const float*)d_in[12];
  const float* b1 = (const float*)d_in[13];
  const float* W2 = (const float*)d_in[14];
  const float* b2 = (const float*)d_in[15];
  float* out = (float*)d_out;

  // workspace carve (all 256B aligned). Total ~26 MB.
  char* p = (char*)d_ws;
  auto carve = [&](size_t bytes) { char* r = p; p += (bytes + 255) & ~(size_t)255; return r; };
  __hip_bfloat16* tb     = (__hip_bfloat16*)carve((size_t)NUM_MOVIES_N * FEAT * 2);
  __hip_bfloat16* WcatT  = (__hip_bfloat16*)carve(256 * 256 * 2);
  __hip_bfloat16* WmT    = (__hip_bfloat16*)carve(256 * 128 * 2);
  __hip_bfloat16* W1T    = (__hip_bfloat16*)carve(256 * 256 * 2);
  __hip_bfloat16* W2T    = (__hip_bfloat16*)carve(128 * 256 * 2);
  float*          bc     = (float*)carve(256 * 4);

  prep_all<<<CONV_BLOCKS + 256, 256, 0, stream>>>(
      table, tb, Wu, Wm, W1, W2, bu, bm, WcatT, WmT, W1T, W2T, bc);
  // 512 s0 blocks (even ids, 32-row tiles) + 512 s1/s2 blocks (odd ids)
  fused_mlp<<<1024, 512, 0, stream>>>(
      users, tb, pos_ids, neg_ids, nbr_ids, WcatT, WmT, W1T, W2T,
      bc, bm, b1, b2, out);
}

// Round 7
// 209.196 us; speedup vs baseline: 1.0456x; 1.0456x over previous
//
#include <hip/hip_runtime.h>
#include <hip/hip_bf16.h>

// Problem constants (from reference)
#define BATCH_N   16384
#define FEAT      128      // MOVIE_FEAT == USER_FEAT
#define NNBR      50
#define NUM_MOVIES_N 100000

typedef short  short8  __attribute__((ext_vector_type(8)));
typedef float  floatx4 __attribute__((ext_vector_type(4)));
typedef unsigned int u32;

__device__ __forceinline__ __hip_bfloat16 f2bf(float x) { return __float2bfloat16(x); }
__device__ __forceinline__ float bfb2f(short s) {
  union { u32 u; float f; } c; c.u = ((u32)(unsigned short)s) << 16; return c.f;
}

// async global->LDS 16B DMA. HW writes wave-uniform base + lane*16 (m104);
// the per-lane pointer we pass must equal that form.
__device__ __forceinline__ void gld16(const __hip_bfloat16* g, __hip_bfloat16* l) {
  __builtin_amdgcn_global_load_lds(
      (const __attribute__((address_space(1))) u32*)g,
      (__attribute__((address_space(3))) u32*)l, 16, 0, 0);
}

__device__ __forceinline__ floatx4 mfma16(short8 a, short8 b, floatx4 c) {
  return __builtin_amdgcn_mfma_f32_16x16x32_bf16(a, b, c, 0, 0, 0);
}

#define WAITVM2 asm volatile("s_waitcnt vmcnt(2)" ::: "memory")
#define WAITVM0 asm volatile("s_waitcnt vmcnt(0)" ::: "memory")

// ---------------------------------------------------------------------------
// prep_all: fused (a) fp32 movie_table -> bf16 copy and (b) bf16 transposed
// weights Wt[n][k] + fused bias bu+bm + gather-done counter reset.
// blocks [0,6250): conv;  [6250,6506): weight prep.
// ---------------------------------------------------------------------------
#define CONV_BLOCKS (NUM_MOVIES_N * FEAT / (256 * 8))   // 6250
__global__ __launch_bounds__(256) void prep_all(
    const float* __restrict__ t, __hip_bfloat16* __restrict__ tb,
    const float* __restrict__ Wu, const float* __restrict__ Wm,
    const float* __restrict__ W1, const float* __restrict__ W2,
    const float* __restrict__ bu, const float* __restrict__ bm,
    __hip_bfloat16* __restrict__ WcatT, __hip_bfloat16* __restrict__ WmT,
    __hip_bfloat16* __restrict__ W1T,  __hip_bfloat16* __restrict__ W2T,
    float* __restrict__ bc, unsigned int* __restrict__ ctr) {
  int bid = blockIdx.x;
  if (bid < CONV_BLOCKS) {
    size_t i = ((size_t)bid * 256 + threadIdx.x) * 8;
    float4 v0 = *(const float4*)(t + i);
    float4 v1 = *(const float4*)(t + i + 4);
    __hip_bfloat16 o[8];
    o[0] = f2bf(v0.x); o[1] = f2bf(v0.y); o[2] = f2bf(v0.z); o[3] = f2bf(v0.w);
    o[4] = f2bf(v1.x); o[5] = f2bf(v1.y); o[6] = f2bf(v1.z); o[7] = f2bf(v1.w);
    *(short8*)(tb + i) = *(short8*)o;
  } else {
    int idx = (bid - CONV_BLOCKS) * 256 + threadIdx.x;   // 0..65535
    int n = idx & 255, k = idx >> 8;
    float v = (k < 128) ? Wu[k * 256 + n] : Wm[(k - 128) * 256 + n];
    WcatT[n * 256 + k] = f2bf(v);
    W1T[n * 256 + k]   = f2bf(W1[k * 256 + n]);
    if (k < 128) WmT[n * 128 + k] = f2bf(Wm[k * 256 + n]);
    if (idx < 32768) {
      int k2 = idx >> 7, n2 = idx & 127;
      W2T[n2 * 256 + k2] = f2bf(W2[k2 * 128 + n2]);
    }
    if (idx < 256) bc[idx] = bu[idx] + bm[idx];
    if (idx == 0) *ctr = 0;                   // reset gather-done counter
  }
}

// ---------------------------------------------------------------------------
// layer: one GEMM layer on a 64-row LDS tile with B persistent in VGPRs.
//   Ain (LDS): 64 rows x K0, XOR-swizzled (16B slot s holds chunk s^(r&7)).
//   Wt: global [NCOL][K0] bf16 (L2-hot; ~16 KB/wave loaded ONCE per layer).
// 8 waves split N: wave w owns JN*16 cols (JN = NCOL/128).
// 4 iters x 16 rows: KK ds_read_b128 + 2*KK*JN MFMA; epilogue -> LDS
// (swizzled, 256-col) or global fp32 (128-col).
// ---------------------------------------------------------------------------
template <int K0, int NCOL, bool RELU, bool TOGLB>
__device__ __forceinline__ void layer(
    const __hip_bfloat16* Ain,
    const __hip_bfloat16* __restrict__ Wt, const float* __restrict__ bias,
    __hip_bfloat16* Olds, float* __restrict__ Oglb,
    int wid, int quad, int lrow) {
  constexpr int KK = K0 / 32;
  constexpr int JN = NCOL / 128;
  const int c0 = wid * JN * 16;

  short8 bfr[JN][KK];
  float  bv[JN];
  #pragma unroll
  for (int j = 0; j < JN; ++j) {
    #pragma unroll
    for (int kc = 0; kc < KK; ++kc)
      bfr[j][kc] = *(const short8*)(Wt + (size_t)(c0 + j * 16 + lrow) * K0 +
                                    kc * 32 + quad * 8);
    bv[j] = bias[c0 + j * 16 + lrow];
  }

  #pragma unroll
  for (int it = 0; it < 4; ++it) {
    int r = it * 16 + lrow;
    short8 af[KK];
    #pragma unroll
    for (int kc = 0; kc < KK; ++kc)
      af[kc] = *(const short8*)&Ain[r * K0 + (((kc * 4 + quad) ^ (r & 7)) << 3)];
    floatx4 pa[JN], pb[JN];
    #pragma unroll
    for (int j = 0; j < JN; ++j) { pa[j] = {}; pb[j] = {}; }
    #pragma unroll
    for (int kc = 0; kc < KK; kc += 2)
      #pragma unroll
      for (int j = 0; j < JN; ++j) {
        pa[j] = mfma16(af[kc],     bfr[j][kc],     pa[j]);
        pb[j] = mfma16(af[kc + 1], bfr[j][kc + 1], pb[j]);
      }
    #pragma unroll
    for (int j = 0; j < JN; ++j) {
      floatx4 a = pa[j] + pb[j];
      int col = c0 + j * 16 + lrow;
      #pragma unroll
      for (int rr = 0; rr < 4; ++rr) {
        int row = it * 16 + quad * 4 + rr;
        float v = a[rr] + bv[j];
        if (RELU) v = fmaxf(v, 0.f);
        if (TOGLB) {
          Oglb[(size_t)row * NCOL + col] = v;
        } else {
          int ch = col >> 3;
          Olds[row * 256 + (((ch ^ (row & 7)) << 3) | (col & 7))] = f2bf(v);
        }
      }
    }
  }
}

// ---------------------------------------------------------------------------
// fused_mlp — R17 producer/consumer split.
//
// Pin history (do not change without re-reading):
//   R10: launch_bounds(512,2) alone -> 88 VGPR, B-loads sunk. R12: (4,4) ->
//   64-VGPR bucket, persistent-B spilled (WRITE 24.6->129.6 MB). (2,2) is
//   the only verified-good codegen. VGPR must stay in [86,128] to keep
//   2 blocks/CU (16 waves) resident.
//
// R17: R15/R16 showed (a) the gather is on the contended side of the L3
// random-access curve (more concurrency -> LESS throughput), and (b) s0
// blocks holding CU slots through gather+layers force pos/neg MLP down to
// ~1 block/CU. Split:
//   blocks [0,256):    PURE gather (R15 pipeline verbatim) -> bf16 mean to
//                      global A_user, release-atomicAdd(ctr), exit early.
//   blocks [256,768):  pos/neg MLP, unchanged R15.
//   blocks [768,1024): user MLP; thread0 acquire-spins until ctr==256, then
//                      stages A_user-mean + users (R11 addressing) + layers.
// Deadlock-free by counting: spinners(256) < guaranteed resident slots(512,
// LDS 64KB -> >=2 blocks/CU), so forward progress is unconditional; no
// dispatch-order assumption (G16-safe). Mean takes the identical
// accumulate/round path -> bit-identical numerics.
// ---------------------------------------------------------------------------
__global__ __launch_bounds__(512)
__attribute__((amdgpu_waves_per_eu(2, 2)))
void fused_mlp(
    const float* __restrict__ users,
    const __hip_bfloat16* __restrict__ tb,
    const int* __restrict__ pos_ids, const int* __restrict__ neg_ids,
    const int* __restrict__ nbr_ids,
    const __hip_bfloat16* __restrict__ WcatT,
    const __hip_bfloat16* __restrict__ WmT,
    const __hip_bfloat16* __restrict__ W1T,
    const __hip_bfloat16* __restrict__ W2T,
    const float* __restrict__ bc, const float* __restrict__ bmv,
    const float* __restrict__ b1, const float* __restrict__ b2,
    __hip_bfloat16* __restrict__ A_user, unsigned int* __restrict__ ctr,
    float* __restrict__ out) {
  __shared__ __hip_bfloat16 A_lds[64 * 256];   // 32 KB: A, then H
  __shared__ __hip_bfloat16 E_lds[64 * 256];   // 32 KB: gather staging / E

  const int t    = threadIdx.x;
  const int lane = t & 63, wid = t >> 6;       // wid 0..7
  const int quad = lane >> 4, lrow = lane & 15;
  const int b    = blockIdx.x;

  if (b < 256) {
    // ================= producer: pure gather -> A_user =================
    const long m0 = (long)b * 64;
    const int rbase = wid << 3;                      // wave owns rows rbase..+7
    const int* nbw = nbr_ids + (size_t)(m0 + rbase) * NNBR;   // 400 ids
    int idreg[7];
    #pragma unroll
    for (int w = 0; w < 7; ++w) {
      int fl = w * 64 + lane;
      idreg[w] = nbw[fl < 8 * NNBR ? fl : 8 * NNBR - 1];
    }
    __hip_bfloat16* stg = E_lds + (wid << 11);       // 4 KB slice (2 x 2 KB)

    auto getid = [&](int fb) -> int {
      int idx = fb + quad;
      int v = __shfl(idreg[fb >> 6], idx & 63, 64);
      if ((fb >> 6) != ((fb + 3) >> 6)) {
        int v2 = __shfl(idreg[(fb + 3) >> 6], idx & 63, 64);
        v = ((idx >> 6) == (fb >> 6)) ? v : v2;
      }
      return v;
    };
    auto issue = [&](int k) {
      int row = k / 7, c = k % 7;
      int id0 = getid(row * NNBR + c * 8);
      int id1 = getid(row * NNBR + c * 8 + 4);
      __hip_bfloat16* dst = stg + ((k & 1) << 10);   // buf k&1 (2 KB)
      gld16(tb + (size_t)id0 * FEAT + (lrow << 3), dst + (lane << 3));
      gld16(tb + (size_t)id1 * FEAT + (lrow << 3), dst + 512 + (lane << 3));
    };

    issue(0); issue(1);                              // fill pipeline (4 DMA)
    float acc[8] = {0.f, 0.f, 0.f, 0.f, 0.f, 0.f, 0.f, 0.f};
    #pragma unroll
    for (int k = 0; k < 56; ++k) {                   // row = k/7, c = k%7
      if (k < 55) { WAITVM2; } else { WAITVM0; }     // chunk k retired
      const __hip_bfloat16* bb = stg + ((k & 1) << 10);
      int c = k % 7;
      short8 x0 = *(const short8*)(bb + (lane << 3));          // j = c*8+quad
      if (c < 6) {
        short8 x1 = *(const short8*)(bb + 512 + (lane << 3));  // j = c*8+4+quad
        #pragma unroll
        for (int e = 0; e < 8; ++e) { acc[e] += bfb2f(x0[e]); acc[e] += bfb2f(x1[e]); }
      } else if (quad < 2) {                         // j = 48+quad only
        #pragma unroll
        for (int e = 0; e < 8; ++e) acc[e] += bfb2f(x0[e]);
      }
      if (c == 6) {                                  // row complete
        int row = k / 7;
        __hip_bfloat16 o[8];
        #pragma unroll
        for (int e = 0; e < 8; ++e) {
          float v = acc[e];
          v += __shfl_xor(v, 16, 64);
          v += __shfl_xor(v, 32, 64);
          o[e] = f2bf(v * (1.f / NNBR));
          acc[e] = 0.f;
        }
        if (quad == 0)                               // bf16 mean -> global
          *(short8*)(A_user + (size_t)(m0 + rbase + row) * 128 + (lrow << 3)) =
              *(short8*)o;
      }
      __builtin_amdgcn_sched_barrier(0);             // ds_reads done before WAR reuse
      if (k + 2 < 56) issue(k + 2);
    }
    WAITVM0;                                         // drain mean stores
    __syncthreads();                                 // all waves' stores retired
    if (t == 0)
      __hip_atomic_fetch_add(ctr, 1u, __ATOMIC_RELEASE, __HIP_MEMORY_SCOPE_AGENT);
    return;                                          // producer exits (no layers)
  }

  if (b < 768) {
    // ================= pos/neg MLP (unchanged R15) =================
    int k = b - 256;
    const int s = 1 + (k & 1);
    const long m0 = (long)(k >> 1) * 64;
    const int* ids = (s == 1) ? pos_ids : neg_ids;
    #pragma unroll
    for (int i = 0; i < 2; ++i) {
      int c = t + i * 512;                     // 1024 slots: r=c>>4, sl=c&15
      int r = c >> 4, sl = c & 15;
      int id = ids[m0 + r];
      gld16(tb + ((size_t)id << 7) + ((sl ^ (r & 7)) << 3),
            A_lds + (c << 3));
    }
    __syncthreads();                           // A staged (vmcnt(0) drain)

    layer<128, 256, false, false>(A_lds, WmT, bmv, E_lds, nullptr,
                                  wid, quad, lrow);
    __syncthreads();
    layer<256, 256, true, false>(E_lds, W1T, b1, A_lds, nullptr,
                                 wid, quad, lrow);
    __syncthreads();
    layer<256, 128, true, true>(A_lds, W2T, b2, nullptr,
                                out + ((size_t)s * BATCH_N + m0) * 128,
                                wid, quad, lrow);
    return;
  }

  // ================= consumer: user MLP =================
  {
    const long m0 = (long)(b - 768) * 64;
    if (t == 0) {
      while (__hip_atomic_load(ctr, __ATOMIC_ACQUIRE, __HIP_MEMORY_SCOPE_AGENT)
             < 256u)
        __builtin_amdgcn_s_sleep(8);
    }
    __syncthreads();                           // A_user visible to all waves

    const int rbase = wid << 3;
    for (int rr = 0; rr < 8; ++rr) {
      const int r = rbase | rr;
      const size_t grow = (size_t)(m0 + r);
      if (quad == 0) {                         // mean -> cols [128,256)
        short8 m = *(const short8*)(A_user + grow * 128 + (lrow << 3));
        int ch = 16 + lrow;
        *(short8*)(A_lds + r * 256 + ((ch ^ (r & 7)) << 3)) = m;
      }
      // users fp32 -> bf16, cols [0,128): lane covers 2 consecutive cols
      float2 uv = ((const float2*)(users + grow * FEAT))[lane];
      __hip_bfloat162 t0; t0.x = f2bf(uv.x); t0.y = f2bf(uv.y);
      int col = lane << 1, ch2 = col >> 3;
      *(__hip_bfloat162*)(A_lds + r * 256 + ((ch2 ^ (r & 7)) << 3) + (col & 7)) = t0;
    }
    __syncthreads();                           // A staged

    layer<256, 256, false, false>(A_lds, WcatT, bc, E_lds, nullptr,
                                  wid, quad, lrow);
    __syncthreads();
    layer<256, 256, true, false>(E_lds, W1T, b1, A_lds, nullptr,
                                 wid, quad, lrow);
    __syncthreads();
    layer<256, 128, true, true>(A_lds, W2T, b2, nullptr,
                                out + (size_t)m0 * 128,
                                wid, quad, lrow);
  }
}

// ---------------------------------------------------------------------------
extern "C" void kernel_launch(void* const* d_in, const int* in_sizes, int n_in,
                              void* d_out, int out_size, void* d_ws, size_t ws_size,
                              hipStream_t stream) {
  const float* users   = (const float*)d_in[0];
  // d_in[1] pos_movies, d_in[2] neg_movies, d_in[3] user_ids: unused by ref
  const int*   pos_ids = (const int*)d_in[4];
  const int*   neg_ids = (const int*)d_in[5];
  const int*   nbr_ids = (const int*)d_in[6];
  const float* table   = (const float*)d_in[7];
  const float* Wu = (const float*)d_in[8];
  const float* bu = (const float*)d_in[9];
  const float* Wm = (const float*)d_in[10];
  const float* bm = (const float*)d_in[11];
  const float* W1 = (const float*)d_in[12];
  const float* b1 = (const float*)d_in[13];
  const float* W2 = (const float*)d_in[14];
  const float* b2 = (const float*)d_in[15];
  float* out = (float*)d_out;

  // workspace carve (all 256B aligned). Total ~30 MB.
  char* p = (char*)d_ws;
  auto carve = [&](size_t bytes) { char* r = p; p += (bytes + 255) & ~(size_t)255; return r; };
  __hip_bfloat16* tb     = (__hip_bfloat16*)carve((size_t)NUM_MOVIES_N * FEAT * 2);
  __hip_bfloat16* WcatT  = (__hip_bfloat16*)carve(256 * 256 * 2);
  __hip_bfloat16* WmT    = (__hip_bfloat16*)carve(256 * 128 * 2);
  __hip_bfloat16* W1T    = (__hip_bfloat16*)carve(256 * 256 * 2);
  __hip_bfloat16* W2T    = (__hip_bfloat16*)carve(128 * 256 * 2);
  float*          bc     = (float*)carve(256 * 4);
  __hip_bfloat16* A_user = (__hip_bfloat16*)carve((size_t)BATCH_N * 128 * 2);
  unsigned int*   ctr    = (unsigned int*)carve(256);

  prep_all<<<CONV_BLOCKS + 256, 256, 0, stream>>>(
      table, tb, Wu, Wm, W1, W2, bu, bm, WcatT, WmT, W1T, W2T, bc, ctr);
  // [0,256) gather producers | [256,768) pos/neg MLP | [768,1024) user MLP
  fused_mlp<<<1024, 512, 0, stream>>>(
      users, tb, pos_ids, neg_ids, nbr_ids, WcatT, WmT, W1T, W2T,
      bc, bm, b1, b2, A_user, ctr, out);
}

// Round 9
// 203.703 us; speedup vs baseline: 1.0738x; 1.0270x over previous
//
#include <hip/hip_runtime.h>
#include <hip/hip_bf16.h>

// Problem constants (from reference)
#define BATCH_N   16384
#define FEAT      128      // MOVIE_FEAT == USER_FEAT
#define NNBR      50
#define NUM_MOVIES_N 100000

typedef short  short8  __attribute__((ext_vector_type(8)));
typedef float  floatx4 __attribute__((ext_vector_type(4)));
typedef unsigned int u32;

__device__ __forceinline__ __hip_bfloat16 f2bf(float x) { return __float2bfloat16(x); }
__device__ __forceinline__ float bfb2f(short s) {
  union { u32 u; float f; } c; c.u = ((u32)(unsigned short)s) << 16; return c.f;
}

// async global->LDS 16B DMA. HW writes wave-uniform base + lane*16 (m104);
// the per-lane pointer we pass must equal that form.
__device__ __forceinline__ void gld16(const __hip_bfloat16* g, __hip_bfloat16* l) {
  __builtin_amdgcn_global_load_lds(
      (const __attribute__((address_space(1))) u32*)g,
      (__attribute__((address_space(3))) u32*)l, 16, 0, 0);
}

__device__ __forceinline__ floatx4 mfma16(short8 a, short8 b, floatx4 c) {
  return __builtin_amdgcn_mfma_f32_16x16x32_bf16(a, b, c, 0, 0, 0);
}

#define WAITVM6 asm volatile("s_waitcnt vmcnt(6)" ::: "memory")
#define WAITVM4 asm volatile("s_waitcnt vmcnt(4)" ::: "memory")
#define WAITVM2 asm volatile("s_waitcnt vmcnt(2)" ::: "memory")
#define WAITVM0 asm volatile("s_waitcnt vmcnt(0)" ::: "memory")

// ---------------------------------------------------------------------------
// prep_all: fused (a) fp32 movie_table -> bf16 copy and (b) bf16 transposed
// weights Wt[n][k] + fused bias bu+bm. blocks [0,6250): conv; rest: weights.
// ---------------------------------------------------------------------------
#define CONV_BLOCKS (NUM_MOVIES_N * FEAT / (256 * 8))   // 6250
__global__ __launch_bounds__(256) void prep_all(
    const float* __restrict__ t, __hip_bfloat16* __restrict__ tb,
    const float* __restrict__ Wu, const float* __restrict__ Wm,
    const float* __restrict__ W1, const float* __restrict__ W2,
    const float* __restrict__ bu, const float* __restrict__ bm,
    __hip_bfloat16* __restrict__ WcatT, __hip_bfloat16* __restrict__ WmT,
    __hip_bfloat16* __restrict__ W1T,  __hip_bfloat16* __restrict__ W2T,
    float* __restrict__ bc) {
  int bid = blockIdx.x;
  if (bid < CONV_BLOCKS) {
    size_t i = ((size_t)bid * 256 + threadIdx.x) * 8;
    float4 v0 = *(const float4*)(t + i);
    float4 v1 = *(const float4*)(t + i + 4);
    __hip_bfloat16 o[8];
    o[0] = f2bf(v0.x); o[1] = f2bf(v0.y); o[2] = f2bf(v0.z); o[3] = f2bf(v0.w);
    o[4] = f2bf(v1.x); o[5] = f2bf(v1.y); o[6] = f2bf(v1.z); o[7] = f2bf(v1.w);
    *(short8*)(tb + i) = *(short8*)o;
  } else {
    int idx = (bid - CONV_BLOCKS) * 256 + threadIdx.x;   // 0..65535
    int n = idx & 255, k = idx >> 8;
    float v = (k < 128) ? Wu[k * 256 + n] : Wm[(k - 128) * 256 + n];
    WcatT[n * 256 + k] = f2bf(v);
    W1T[n * 256 + k]   = f2bf(W1[k * 256 + n]);
    if (k < 128) WmT[n * 128 + k] = f2bf(Wm[k * 256 + n]);
    if (idx < 32768) {
      int k2 = idx >> 7, n2 = idx & 127;
      W2T[n2 * 256 + k2] = f2bf(W2[k2 * 128 + n2]);
    }
    if (idx < 256) bc[idx] = bu[idx] + bm[idx];
  }
}

// ---------------------------------------------------------------------------
// layer: one GEMM layer on a 64-row LDS tile with B persistent in VGPRs.
//   Ain (LDS): 64 rows x K0, XOR-swizzled (16B slot s holds chunk s^(r&7)).
//   Wt: global [NCOL][K0] bf16 (L2-hot; ~16 KB/wave loaded ONCE per layer).
// 8 waves split N: wave w owns JN*16 cols (JN = NCOL/128).
// 4 iters x 16 rows: KK ds_read_b128 + 2*KK*JN MFMA; epilogue -> LDS
// (swizzled, 256-col) or global fp32 (128-col).
// ---------------------------------------------------------------------------
template <int K0, int NCOL, bool RELU, bool TOGLB>
__device__ __forceinline__ void layer(
    const __hip_bfloat16* Ain,
    const __hip_bfloat16* __restrict__ Wt, const float* __restrict__ bias,
    __hip_bfloat16* Olds, float* __restrict__ Oglb,
    int wid, int quad, int lrow) {
  constexpr int KK = K0 / 32;
  constexpr int JN = NCOL / 128;
  const int c0 = wid * JN * 16;

  short8 bfr[JN][KK];
  float  bv[JN];
  #pragma unroll
  for (int j = 0; j < JN; ++j) {
    #pragma unroll
    for (int kc = 0; kc < KK; ++kc)
      bfr[j][kc] = *(const short8*)(Wt + (size_t)(c0 + j * 16 + lrow) * K0 +
                                    kc * 32 + quad * 8);
    bv[j] = bias[c0 + j * 16 + lrow];
  }

  #pragma unroll
  for (int it = 0; it < 4; ++it) {
    int r = it * 16 + lrow;
    short8 af[KK];
    #pragma unroll
    for (int kc = 0; kc < KK; ++kc)
      af[kc] = *(const short8*)&Ain[r * K0 + (((kc * 4 + quad) ^ (r & 7)) << 3)];
    floatx4 pa[JN], pb[JN];
    #pragma unroll
    for (int j = 0; j < JN; ++j) { pa[j] = {}; pb[j] = {}; }
    #pragma unroll
    for (int kc = 0; kc < KK; kc += 2)
      #pragma unroll
      for (int j = 0; j < JN; ++j) {
        pa[j] = mfma16(af[kc],     bfr[j][kc],     pa[j]);
        pb[j] = mfma16(af[kc + 1], bfr[j][kc + 1], pb[j]);
      }
    #pragma unroll
    for (int j = 0; j < JN; ++j) {
      floatx4 a = pa[j] + pb[j];
      int col = c0 + j * 16 + lrow;
      #pragma unroll
      for (int rr = 0; rr < 4; ++rr) {
        int row = it * 16 + quad * 4 + rr;
        float v = a[rr] + bv[j];
        if (RELU) v = fmaxf(v, 0.f);
        if (TOGLB) {
          Oglb[(size_t)row * NCOL + col] = v;
        } else {
          int ch = col >> 3;
          Olds[row * 256 + (((ch ^ (row & 7)) << 3) | (col & 7))] = f2bf(v);
        }
      }
    }
  }
}

// ---------------------------------------------------------------------------
// fused_mlp — R19 == R18 resubmitted (R18's bench was an infra failure: no
// pytest phase / timing block in the result; static re-audit found no
// defect). R15 structure (s0 blocks [0,256) fused gather+layers; no global
// sync; pos/neg [256,768)), gather pipeline deepened 2x.
//
// Pin history (do not change): R10 launch_bounds-only -> 88 VGPR sink;
// R12 (4,4) -> 64-VGPR spill. (2,2) is the only verified-good codegen.
// Structure history: R16 (gathers spread across generations) and R17
// (producer/consumer global barrier) both regressed; R15 (all gathers at
// t=0, per-block fused consume) is the verified optimum at depth 4 KB/wave.
//
// R18/R19 change vs R15: staging uses the FULL 64 KB LDS (8 KB/wave =
// 4 x 2 KB buffers) -> 4 chunks / 8 gld16 in flight (vmcnt(6) steady,
// 4/2/0 tail). vmcnt safety with interleaved mean-stores: at each
// WAITVM6, chunk k's 2 loads have >=6 younger vmem ops behind them
// (loads k+1..k+3 plus any younger stores/spills) -> FIFO guarantees
// chunk k retired; extra compiler vmem ops only make the wait MORE
// conservative. WAR on buf reuse identical to verified R15 pattern.
// Means bounce through global A_user (same accumulate/round path ->
// bit-identical); users loaded in the consumer phase. After __syncthreads
// staging is dead and A/E reuse the same 64 KB.
// ---------------------------------------------------------------------------
__global__ __launch_bounds__(512)
__attribute__((amdgpu_waves_per_eu(2, 2)))
void fused_mlp(
    const float* __restrict__ users,
    const __hip_bfloat16* __restrict__ tb,
    const int* __restrict__ pos_ids, const int* __restrict__ neg_ids,
    const int* __restrict__ nbr_ids,
    const __hip_bfloat16* __restrict__ WcatT,
    const __hip_bfloat16* __restrict__ WmT,
    const __hip_bfloat16* __restrict__ W1T,
    const __hip_bfloat16* __restrict__ W2T,
    const float* __restrict__ bc, const float* __restrict__ bmv,
    const float* __restrict__ b1, const float* __restrict__ b2,
    __hip_bfloat16* __restrict__ A_user,
    float* __restrict__ out) {
  __shared__ __hip_bfloat16 LDS[64 * 512];     // 64 KB
  __hip_bfloat16* A_lds = LDS;                 // 32 KB: A, then H
  __hip_bfloat16* E_lds = LDS + 64 * 256;      // 32 KB: E
  const int t    = threadIdx.x;
  const int lane = t & 63, wid = t >> 6;       // wid 0..7
  const int quad = lane >> 4, lrow = lane & 15;
  const int b    = blockIdx.x;

  if (b < 256) {
    // ============ s0: deep-pipelined gather -> A_user, then layers ========
    const long m0 = (long)b * 64;
    const int rbase = wid << 3;                      // wave owns rows rbase..+7
    const int* nbw = nbr_ids + (size_t)(m0 + rbase) * NNBR;   // 400 ids
    int idreg[7];
    #pragma unroll
    for (int w = 0; w < 7; ++w) {
      int fl = w * 64 + lane;
      idreg[w] = nbw[fl < 8 * NNBR ? fl : 8 * NNBR - 1];
    }
    __hip_bfloat16* stg = LDS + (wid << 12);         // 8 KB slice (4 x 2 KB)

    auto getid = [&](int fb) -> int {
      int idx = fb + quad;
      int v = __shfl(idreg[fb >> 6], idx & 63, 64);
      if ((fb >> 6) != ((fb + 3) >> 6)) {
        int v2 = __shfl(idreg[(fb + 3) >> 6], idx & 63, 64);
        v = ((idx >> 6) == (fb >> 6)) ? v : v2;
      }
      return v;
    };
    auto issue = [&](int k) {
      int row = k / 7, c = k % 7;
      int id0 = getid(row * NNBR + c * 8);
      int id1 = getid(row * NNBR + c * 8 + 4);
      __hip_bfloat16* dst = stg + ((k & 3) << 10);   // buf k&3 (2 KB)
      gld16(tb + (size_t)id0 * FEAT + (lrow << 3), dst + (lane << 3));
      gld16(tb + (size_t)id1 * FEAT + (lrow << 3), dst + 512 + (lane << 3));
    };

    issue(0); issue(1); issue(2); issue(3);          // fill pipeline (8 DMA)
    float acc[8] = {0.f, 0.f, 0.f, 0.f, 0.f, 0.f, 0.f, 0.f};
    #pragma unroll
    for (int k = 0; k < 56; ++k) {                   // row = k/7, c = k%7
      if (k <= 52)      { WAITVM6; }                 // chunk k retired
      else if (k == 53) { WAITVM4; }
      else if (k == 54) { WAITVM2; }
      else              { WAITVM0; }
      const __hip_bfloat16* bb = stg + ((k & 3) << 10);
      int c = k % 7;
      short8 x0 = *(const short8*)(bb + (lane << 3));          // j = c*8+quad
      if (c < 6) {
        short8 x1 = *(const short8*)(bb + 512 + (lane << 3));  // j = c*8+4+quad
        #pragma unroll
        for (int e = 0; e < 8; ++e) { acc[e] += bfb2f(x0[e]); acc[e] += bfb2f(x1[e]); }
      } else if (quad < 2) {                         // j = 48+quad only
        #pragma unroll
        for (int e = 0; e < 8; ++e) acc[e] += bfb2f(x0[e]);
      }
      if (c == 6) {                                  // row complete
        int row = k / 7;
        __hip_bfloat16 o[8];
        #pragma unroll
        for (int e = 0; e < 8; ++e) {
          float v = acc[e];
          v += __shfl_xor(v, 16, 64);
          v += __shfl_xor(v, 32, 64);
          o[e] = f2bf(v * (1.f / NNBR));
          acc[e] = 0.f;
        }
        if (quad == 0)                               // bf16 mean -> global
          *(short8*)(A_user + (size_t)(m0 + rbase + row) * 128 + (lrow << 3)) =
              *(short8*)o;
      }
      __builtin_amdgcn_sched_barrier(0);             // ds_reads done before WAR reuse
      if (k + 4 < 56) issue(k + 4);
    }
    WAITVM0;                                         // drain mean stores
    __syncthreads();                                 // staging dead; A/E reuse LDS

    // ---- consumer: stage A (means L2-hot + users) and run the 3 layers ----
    for (int rr = 0; rr < 8; ++rr) {
      const int r = rbase | rr;
      const size_t grow = (size_t)(m0 + r);
      if (quad == 0) {                               // mean -> cols [128,256)
        short8 m = *(const short8*)(A_user + grow * 128 + (lrow << 3));
        int ch = 16 + lrow;
        *(short8*)(A_lds + r * 256 + ((ch ^ (r & 7)) << 3)) = m;
      }
      float2 uv = ((const float2*)(users + grow * FEAT))[lane];
      __hip_bfloat162 t0; t0.x = f2bf(uv.x); t0.y = f2bf(uv.y);
      int col = lane << 1, ch2 = col >> 3;
      *(__hip_bfloat162*)(A_lds + r * 256 + ((ch2 ^ (r & 7)) << 3) + (col & 7)) = t0;
    }
    __syncthreads();                                 // A staged

    layer<256, 256, false, false>(A_lds, WcatT, bc, E_lds, nullptr,
                                  wid, quad, lrow);
    __syncthreads();
    layer<256, 256, true, false>(E_lds, W1T, b1, A_lds, nullptr,
                                 wid, quad, lrow);
    __syncthreads();
    layer<256, 128, true, true>(A_lds, W2T, b2, nullptr,
                                out + (size_t)m0 * 128,
                                wid, quad, lrow);
    return;
  }

  // ================= pos/neg MLP (unchanged R15) =================
  {
    int k = b - 256;
    const int s = 1 + (k & 1);
    const long m0 = (long)(k >> 1) * 64;
    const int* ids = (s == 1) ? pos_ids : neg_ids;
    #pragma unroll
    for (int i = 0; i < 2; ++i) {
      int c = t + i * 512;                     // 1024 slots: r=c>>4, sl=c&15
      int r = c >> 4, sl = c & 15;
      int id = ids[m0 + r];
      gld16(tb + ((size_t)id << 7) + ((sl ^ (r & 7)) << 3),
            A_lds + (c << 3));
    }
    __syncthreads();                           // A staged (vmcnt(0) drain)

    layer<128, 256, false, false>(A_lds, WmT, bmv, E_lds, nullptr,
                                  wid, quad, lrow);
    __syncthreads();
    layer<256, 256, true, false>(E_lds, W1T, b1, A_lds, nullptr,
                                 wid, quad, lrow);
    __syncthreads();
    layer<256, 128, true, true>(A_lds, W2T, b2, nullptr,
                                out + ((size_t)s * BATCH_N + m0) * 128,
                                wid, quad, lrow);
  }
}

// ---------------------------------------------------------------------------
extern "C" void kernel_launch(void* const* d_in, const int* in_sizes, int n_in,
                              void* d_out, int out_size, void* d_ws, size_t ws_size,
                              hipStream_t stream) {
  const float* users   = (const float*)d_in[0];
  // d_in[1] pos_movies, d_in[2] neg_movies, d_in[3] user_ids: unused by ref
  const int*   pos_ids = (const int*)d_in[4];
  const int*   neg_ids = (const int*)d_in[5];
  const int*   nbr_ids = (const int*)d_in[6];
  const float* table   = (const float*)d_in[7];
  const float* Wu = (const float*)d_in[8];
  const float* bu = (const float*)d_in[9];
  const float* Wm = (const float*)d_in[10];
  const float* bm = (const float*)d_in[11];
  const float* W1 = (const float*)d_in[12];
  const float* b1 = (const float*)d_in[13];
  const float* W2 = (const float*)d_in[14];
  const float* b2 = (const float*)d_in[15];
  float* out = (float*)d_out;

  // workspace carve (all 256B aligned). Total ~30 MB.
  char* p = (char*)d_ws;
  auto carve = [&](size_t bytes) { char* r = p; p += (bytes + 255) & ~(size_t)255; return r; };
  __hip_bfloat16* tb     = (__hip_bfloat16*)carve((size_t)NUM_MOVIES_N * FEAT * 2);
  __hip_bfloat16* WcatT  = (__hip_bfloat16*)carve(256 * 256 * 2);
  __hip_bfloat16* WmT    = (__hip_bfloat16*)carve(256 * 128 * 2);
  __hip_bfloat16* W1T    = (__hip_bfloat16*)carve(256 * 256 * 2);
  __hip_bfloat16* W2T    = (__hip_bfloat16*)carve(128 * 256 * 2);
  float*          bc     = (float*)carve(256 * 4);
  __hip_bfloat16* A_user = (__hip_bfloat16*)carve((size_t)BATCH_N * 128 * 2);

  prep_all<<<CONV_BLOCKS + 256, 256, 0, stream>>>(
      table, tb, Wu, Wm, W1, W2, bu, bm, WcatT, WmT, W1T, W2T, bc);
  // [0,256) fused gather+user-MLP | [256,768) pos/neg MLP
  fused_mlp<<<768, 512, 0, stream>>>(
      users, tb, pos_ids, neg_ids, nbr_ids, WcatT, WmT, W1T, W2T,
      bc, bm, b1, b2, A_user, out);
}

// Round 10
// 195.329 us; speedup vs baseline: 1.1199x; 1.0429x over previous
//
#include <hip/hip_runtime.h>
#include <hip/hip_bf16.h>

// Problem constants (from reference)
#define BATCH_N   16384
#define FEAT      128      // MOVIE_FEAT == USER_FEAT
#define NNBR      50
#define NUM_MOVIES_N 100000

typedef short  short8  __attribute__((ext_vector_type(8)));
typedef float  floatx4 __attribute__((ext_vector_type(4)));
typedef unsigned int u32;

__device__ __forceinline__ __hip_bfloat16 f2bf(float x) { return __float2bfloat16(x); }
__device__ __forceinline__ float bfb2f(short s) {
  union { u32 u; float f; } c; c.u = ((u32)(unsigned short)s) << 16; return c.f;
}

// async global->LDS 16B DMA. HW writes wave-uniform base + lane*16 (m104);
// the per-lane pointer we pass must equal that form.
__device__ __forceinline__ void gld16(const __hip_bfloat16* g, __hip_bfloat16* l) {
  __builtin_amdgcn_global_load_lds(
      (const __attribute__((address_space(1))) u32*)g,
      (__attribute__((address_space(3))) u32*)l, 16, 0, 0);
}

__device__ __forceinline__ floatx4 mfma16(short8 a, short8 b, floatx4 c) {
  return __builtin_amdgcn_mfma_f32_16x16x32_bf16(a, b, c, 0, 0, 0);
}

#define WAITVM2 asm volatile("s_waitcnt vmcnt(2)" ::: "memory")
#define WAITVM0 asm volatile("s_waitcnt vmcnt(0)" ::: "memory")

// ---------------------------------------------------------------------------
// prep_all: fused (a) fp32 movie_table -> bf16 copy and (b) bf16 transposed
// weights Wt[n][k] + fused bias bu+bm. One launch instead of two.
// blocks [0,6250): conv;  [6250,6506): weight prep.
// ---------------------------------------------------------------------------
#define CONV_BLOCKS (NUM_MOVIES_N * FEAT / (256 * 8))   // 6250
__global__ __launch_bounds__(256) void prep_all(
    const float* __restrict__ t, __hip_bfloat16* __restrict__ tb,
    const float* __restrict__ Wu, const float* __restrict__ Wm,
    const float* __restrict__ W1, const float* __restrict__ W2,
    const float* __restrict__ bu, const float* __restrict__ bm,
    __hip_bfloat16* __restrict__ WcatT, __hip_bfloat16* __restrict__ WmT,
    __hip_bfloat16* __restrict__ W1T,  __hip_bfloat16* __restrict__ W2T,
    float* __restrict__ bc) {
  int bid = blockIdx.x;
  if (bid < CONV_BLOCKS) {
    size_t i = ((size_t)bid * 256 + threadIdx.x) * 8;
    float4 v0 = *(const float4*)(t + i);
    float4 v1 = *(const float4*)(t + i + 4);
    __hip_bfloat16 o[8];
    o[0] = f2bf(v0.x); o[1] = f2bf(v0.y); o[2] = f2bf(v0.z); o[3] = f2bf(v0.w);
    o[4] = f2bf(v1.x); o[5] = f2bf(v1.y); o[6] = f2bf(v1.z); o[7] = f2bf(v1.w);
    *(short8*)(tb + i) = *(short8*)o;
  } else {
    int idx = (bid - CONV_BLOCKS) * 256 + threadIdx.x;   // 0..65535
    int n = idx & 255, k = idx >> 8;
    float v = (k < 128) ? Wu[k * 256 + n] : Wm[(k - 128) * 256 + n];
    WcatT[n * 256 + k] = f2bf(v);
    W1T[n * 256 + k]   = f2bf(W1[k * 256 + n]);
    if (k < 128) WmT[n * 128 + k] = f2bf(Wm[k * 256 + n]);
    if (idx < 32768) {
      int k2 = idx >> 7, n2 = idx & 127;
      W2T[n2 * 256 + k2] = f2bf(W2[k2 * 128 + n2]);
    }
    if (idx < 256) bc[idx] = bu[idx] + bm[idx];
  }
}

// ---------------------------------------------------------------------------
// layer: one GEMM layer on a 64-row LDS tile with B persistent in VGPRs.
//   Ain (LDS): 64 rows x K0, XOR-swizzled (16B slot s holds chunk s^(r&7)).
//   Wt: global [NCOL][K0] bf16 (L2-hot; ~16 KB/wave loaded ONCE per layer).
// 8 waves split N: wave w owns JN*16 cols (JN = NCOL/128).
// 4 iters x 16 rows: KK ds_read_b128 + 2*KK*JN MFMA; epilogue -> LDS
// (swizzled, 256-col) or global fp32 (128-col).
// ---------------------------------------------------------------------------
template <int K0, int NCOL, bool RELU, bool TOGLB>
__device__ __forceinline__ void layer(
    const __hip_bfloat16* Ain,
    const __hip_bfloat16* __restrict__ Wt, const float* __restrict__ bias,
    __hip_bfloat16* Olds, float* __restrict__ Oglb,
    int wid, int quad, int lrow) {
  constexpr int KK = K0 / 32;
  constexpr int JN = NCOL / 128;
  const int c0 = wid * JN * 16;

  short8 bfr[JN][KK];
  float  bv[JN];
  #pragma unroll
  for (int j = 0; j < JN; ++j) {
    #pragma unroll
    for (int kc = 0; kc < KK; ++kc)
      bfr[j][kc] = *(const short8*)(Wt + (size_t)(c0 + j * 16 + lrow) * K0 +
                                    kc * 32 + quad * 8);
    bv[j] = bias[c0 + j * 16 + lrow];
  }

  #pragma unroll
  for (int it = 0; it < 4; ++it) {
    int r = it * 16 + lrow;
    short8 af[KK];
    #pragma unroll
    for (int kc = 0; kc < KK; ++kc)
      af[kc] = *(const short8*)&Ain[r * K0 + (((kc * 4 + quad) ^ (r & 7)) << 3)];
    floatx4 pa[JN], pb[JN];
    #pragma unroll
    for (int j = 0; j < JN; ++j) { pa[j] = {}; pb[j] = {}; }
    #pragma unroll
    for (int kc = 0; kc < KK; kc += 2)
      #pragma unroll
      for (int j = 0; j < JN; ++j) {
        pa[j] = mfma16(af[kc],     bfr[j][kc],     pa[j]);
        pb[j] = mfma16(af[kc + 1], bfr[j][kc + 1], pb[j]);
      }
    #pragma unroll
    for (int j = 0; j < JN; ++j) {
      floatx4 a = pa[j] + pb[j];
      int col = c0 + j * 16 + lrow;
      #pragma unroll
      for (int rr = 0; rr < 4; ++rr) {
        int row = it * 16 + quad * 4 + rr;
        float v = a[rr] + bv[j];
        if (RELU) v = fmaxf(v, 0.f);
        if (TOGLB) {
          Oglb[(size_t)row * NCOL + col] = v;
        } else {
          int ch = col >> 3;
          Olds[row * 256 + (((ch ^ (row & 7)) << 3) | (col & 7))] = f2bf(v);
        }
      }
    }
  }
}

// ---------------------------------------------------------------------------
// fused_mlp — R20 == R15 restored (the session champion, 193.4 us total).
//
// Pin history (do not change): R10 launch_bounds-only -> 88 VGPR sink;
// R12 (4,4) -> 64-VGPR spill. (2,2) is the only verified-good codegen.
//
// Structure history (all measured):
//   R15 (this): s0 [0,256) fused gather+layers, 4KB/wave vmcnt(2) dbuf,
//               pos/neg [256,768) -> fused 68.5, total 193.4. CHAMPION.
//   R16: 32-row s0 tiles interleaved -> gather tput DROPPED (1.37 TB/s), 93us.
//   R17: producer/consumer global-flag split -> dead spin slots, 81us.
//   R19: 8KB/wave depth + A_user bounce -> 74us.
// Constraint chain: layer needs ~100 VGPR -> 128-reg bucket -> 16 waves/CU;
// sub-64-VGPR escapes catastrophic (R10/R12); at 16 waves/CU gather caps at
// ~8 waves/CU -> ~1.9 TB/s beyond-L2, depth-invariant (R14/R15/R19); gather
// beyond-L2 traffic (~99MB) compulsory (per-XCD working set 16.4MB >> 4MB L2).
// fused ~= 99MB/1.9TB/s + tail ~= 68us. This is the structure's floor.
// ---------------------------------------------------------------------------
__global__ __launch_bounds__(512)
__attribute__((amdgpu_waves_per_eu(2, 2)))
void fused_mlp(
    const float* __restrict__ users,
    const __hip_bfloat16* __restrict__ tb,
    const int* __restrict__ pos_ids, const int* __restrict__ neg_ids,
    const int* __restrict__ nbr_ids,
    const __hip_bfloat16* __restrict__ WcatT,
    const __hip_bfloat16* __restrict__ WmT,
    const __hip_bfloat16* __restrict__ W1T,
    const __hip_bfloat16* __restrict__ W2T,
    const float* __restrict__ bc, const float* __restrict__ bmv,
    const float* __restrict__ b1, const float* __restrict__ b2,
    float* __restrict__ out) {
  __shared__ __hip_bfloat16 A_lds[64 * 256];   // 32 KB: A, then H
  __shared__ __hip_bfloat16 E_lds[64 * 256];   // 32 KB: gather staging / E

  const int t    = threadIdx.x;
  const int lane = t & 63, wid = t >> 6;       // wid 0..7
  const int quad = lane >> 4, lrow = lane & 15;

  // front-loaded stream mapping: [0,256) -> s0; [256,768) -> s1/s2 interleaved
  int s, tile;
  if (blockIdx.x < 256) { s = 0; tile = blockIdx.x; }
  else { int k = blockIdx.x - 256; s = 1 + (k & 1); tile = k >> 1; }
  const long m0 = (long)tile * 64;

  // ---- stage A tile ----
  if (s == 0) {
    const int rbase = wid << 3;                      // wave owns rows rbase..+7
    const int* nbw = nbr_ids + (size_t)(m0 + rbase) * NNBR;   // 400 ids
    int idreg[7];
    #pragma unroll
    for (int w = 0; w < 7; ++w) {
      int fl = w * 64 + lane;
      idreg[w] = nbw[fl < 8 * NNBR ? fl : 8 * NNBR - 1];
    }
    // user rows (8 loads; retire under the pipeline, used at row ends)
    float2 uvr[8];
    #pragma unroll
    for (int r = 0; r < 8; ++r)
      uvr[r] = ((const float2*)(users + (size_t)(m0 + rbase + r) * FEAT))[lane];

    __hip_bfloat16* stg = E_lds + (wid << 11);       // 4 KB slice (2 x 2 KB)

    // id for 4 consecutive flat slots [fb, fb+3], lane picks fb+quad.
    auto getid = [&](int fb) -> int {
      int idx = fb + quad;
      int v = __shfl(idreg[fb >> 6], idx & 63, 64);
      if ((fb >> 6) != ((fb + 3) >> 6)) {
        int v2 = __shfl(idreg[(fb + 3) >> 6], idx & 63, 64);
        v = ((idx >> 6) == (fb >> 6)) ? v : v2;
      }
      return v;
    };
    // chunk k: rows j = c*8 + i*4 + quad (i=0,1), slice lrow; 2 x 1 KB DMA.
    auto issue = [&](int k) {
      int row = k / 7, c = k % 7;
      int id0 = getid(row * NNBR + c * 8);
      int id1 = getid(row * NNBR + c * 8 + 4);
      __hip_bfloat16* dst = stg + ((k & 1) << 10);   // buf k&1 (2 KB)
      gld16(tb + (size_t)id0 * FEAT + (lrow << 3), dst + (lane << 3));
      gld16(tb + (size_t)id1 * FEAT + (lrow << 3), dst + 512 + (lane << 3));
    };

    issue(0); issue(1);                              // fill pipeline (4 DMA)
    float acc[8] = {0.f, 0.f, 0.f, 0.f, 0.f, 0.f, 0.f, 0.f};
    #pragma unroll
    for (int k = 0; k < 56; ++k) {                   // row = k/7, c = k%7
      if (k < 55) { WAITVM2; } else { WAITVM0; }     // chunk k retired
      const __hip_bfloat16* bb = stg + ((k & 1) << 10);
      int c = k % 7;
      short8 x0 = *(const short8*)(bb + (lane << 3));          // j = c*8+quad
      if (c < 6) {
        short8 x1 = *(const short8*)(bb + 512 + (lane << 3));  // j = c*8+4+quad
        #pragma unroll
        for (int e = 0; e < 8; ++e) { acc[e] += bfb2f(x0[e]); acc[e] += bfb2f(x1[e]); }
      } else if (quad < 2) {                         // j = 48+quad only
        #pragma unroll
        for (int e = 0; e < 8; ++e) acc[e] += bfb2f(x0[e]);
      }
      if (c == 6) {                                  // row complete
        int row = k / 7, r = rbase + row;
        __hip_bfloat16 o[8];
        #pragma unroll
        for (int e = 0; e < 8; ++e) {
          float v = acc[e];
          v += __shfl_xor(v, 16, 64);
          v += __shfl_xor(v, 32, 64);
          o[e] = f2bf(v * (1.f / NNBR));
          acc[e] = 0.f;
        }
        if (quad == 0) {
          int ch = 16 + lrow;                        // cols [128,256)
          *(short8*)(A_lds + r * 256 + ((ch ^ (r & 7)) << 3)) = *(short8*)o;
        }
        float2 uv = uvr[row];                        // cols [0,128)
        __hip_bfloat162 t0; t0.x = f2bf(uv.x); t0.y = f2bf(uv.y);
        int col = lane << 1, ch2 = col >> 3;
        *(__hip_bfloat162*)(A_lds + r * 256 + ((ch2 ^ (r & 7)) << 3) + (col & 7)) = t0;
      }
      __builtin_amdgcn_sched_barrier(0);             // ds_reads done before WAR reuse
      if (k + 2 < 56) issue(k + 2);
    }
  } else {
    const int* ids = (s == 1) ? pos_ids : neg_ids;
    #pragma unroll
    for (int i = 0; i < 2; ++i) {
      int c = t + i * 512;                     // 1024 slots: r=c>>4, sl=c&15
      int r = c >> 4, sl = c & 15;
      int id = ids[m0 + r];
      gld16(tb + ((size_t)id << 7) + ((sl ^ (r & 7)) << 3),
            A_lds + (c << 3));
    }
  }
  __syncthreads();                             // A staged (vmcnt(0) drain / LDS writes)

  // ---- layer 0 -> E_lds (no relu) ----
  if (s == 0)
    layer<256, 256, false, false>(A_lds, WcatT, bc, E_lds, nullptr,
                                  wid, quad, lrow);
  else
    layer<128, 256, false, false>(A_lds, WmT, bmv, E_lds, nullptr,
                                  wid, quad, lrow);
  __syncthreads();                             // E complete (A reads done)

  // ---- layer 1: H = relu(E @ W1^T + b1) -> A_lds ----
  layer<256, 256, true, false>(E_lds, W1T, b1, A_lds, nullptr,
                               wid, quad, lrow);
  __syncthreads();                             // H complete

  // ---- layer 2: out = relu(H @ W2^T + b2) -> global fp32 ----
  layer<256, 128, true, true>(A_lds, W2T, b2, nullptr,
                              out + ((size_t)s * BATCH_N + m0) * 128,
                              wid, quad, lrow);
}

// ---------------------------------------------------------------------------
extern "C" void kernel_launch(void* const* d_in, const int* in_sizes, int n_in,
                              void* d_out, int out_size, void* d_ws, size_t ws_size,
                              hipStream_t stream) {
  const float* users   = (const float*)d_in[0];
  // d_in[1] pos_movies, d_in[2] neg_movies, d_in[3] user_ids: unused by ref
  const int*   pos_ids = (const int*)d_in[4];
  const int*   neg_ids = (const int*)d_in[5];
  const int*   nbr_ids = (const int*)d_in[6];
  const float* table   = (const float*)d_in[7];
  const float* Wu = (const float*)d_in[8];
  const float* bu = (const float*)d_in[9];
  const float* Wm = (const float*)d_in[10];
  const float* bm = (const float*)d_in[11];
  const float* W1 = (const float*)d_in[12];
  const float* b1 = (const float*)d_in[13];
  const float* W2 = (const float*)d_in[14];
  const float* b2 = (const float*)d_in[15];
  float* out = (float*)d_out;

  // workspace carve (all 256B aligned). Total ~26 MB.
  char* p = (char*)d_ws;
  auto carve = [&](size_t bytes) { char* r = p; p += (bytes + 255) & ~(size_t)255; return r; };
  __hip_bfloat16* tb     = (__hip_bfloat16*)carve((size_t)NUM_MOVIES_N * FEAT * 2);
  __hip_bfloat16* WcatT  = (__hip_bfloat16*)carve(256 * 256 * 2);
  __hip_bfloat16* WmT    = (__hip_bfloat16*)carve(256 * 128 * 2);
  __hip_bfloat16* W1T    = (__hip_bfloat16*)carve(256 * 256 * 2);
  __hip_bfloat16* W2T    = (__hip_bfloat16*)carve(128 * 256 * 2);
  float*          bc     = (float*)carve(256 * 4);

  prep_all<<<CONV_BLOCKS + 256, 256, 0, stream>>>(
      table, tb, Wu, Wm, W1, W2, bu, bm, WcatT, WmT, W1T, W2T, bc);
  fused_mlp<<<768, 512, 0, stream>>>(
      users, tb, pos_ids, neg_ids, nbr_ids, WcatT, WmT, W1T, W2T,
      bc, bm, b1, b2, out);
}